// Round 1
// baseline (142.817 us; speedup 1.0000x reference)
//
#include <hip/hip_runtime.h>

#define BB 64
#define TT 8192
#define CC 64

// ---------------- K1: masked argmax over C=64 -> preds[B*T] ----------------
// 16 lanes per frame, float4 loads (16B/lane). Tie-break: first (lowest) index.
__global__ __launch_bounds__(256) void k_argmax(const float* __restrict__ logits,
                                                const int* __restrict__ mask,
                                                int* __restrict__ preds) {
    const int lane = threadIdx.x & 63;
    const int wave = threadIdx.x >> 6;
    const int sub  = lane & 15;   // column group within frame
    const int fidx = lane >> 4;   // frame within group of 4
    const int wavesPerBlock = blockDim.x >> 6;
    const int gw = blockIdx.x * wavesPerBlock + wave;
    const int nw = gridDim.x * wavesPerBlock;
    const int ngroups = (BB * TT) >> 2;   // 4 frames per wave-iteration

    for (int g = gw; g < ngroups; g += nw) {
        const int f = g * 4 + fidx;
        const float4 v = *reinterpret_cast<const float4*>(
            logits + (size_t)f * CC + sub * 4);
        float bv = v.x; int bi = sub * 4;
        if (v.y > bv) { bv = v.y; bi = sub * 4 + 1; }
        if (v.z > bv) { bv = v.z; bi = sub * 4 + 2; }
        if (v.w > bv) { bv = v.w; bi = sub * 4 + 3; }
        // reduce across the 16 lanes of this frame (xor keeps us in-group)
        #pragma unroll
        for (int off = 1; off < 16; off <<= 1) {
            float ov = __shfl_xor(bv, off);
            int   oi = __shfl_xor(bi, off);
            if (ov > bv || (ov == bv && oi < bi)) { bv = ov; bi = oi; }
        }
        if (sub == 0) {
            preds[f] = mask[f] ? -1 : bi;
        }
    }
}

// ---------------- K2: per-batch RLE + compaction scans ----------------
// One block per batch. LDS: preds row (32K) + seg_start (32K) + scan partials.
__global__ __launch_bounds__(256) void k_rle(const int* __restrict__ preds,
                                             int* __restrict__ g_start,
                                             int* __restrict__ g_count,
                                             int* __restrict__ g_newsz) {
    __shared__ int s_pred[TT];
    __shared__ int s_start[TT];
    __shared__ int s_part[256];
    const int b   = blockIdx.x;
    const int tid = threadIdx.x;
    const int CHUNK = TT / 256;     // 32
    const int t0 = tid * CHUNK;

    // load preds row (int4 vectorized)
    {
        const int4* src = reinterpret_cast<const int4*>(preds + (size_t)b * TT);
        int4* dst = reinterpret_cast<int4*>(s_pred);
        for (int i = tid; i < TT / 4; i += 256) dst[i] = src[i];
    }
    __syncthreads();

    // ---- scan 1: boundaries -> segment starts ----
    int local = 0;
    for (int t = t0; t < t0 + CHUNK; ++t) {
        int bnd = (t == 0) || (s_pred[t] != s_pred[t - 1]);
        local += bnd;
    }
    s_part[tid] = local;
    __syncthreads();
    for (int off = 1; off < 256; off <<= 1) {
        int v = (tid >= off) ? s_part[tid - off] : 0;
        __syncthreads();
        s_part[tid] += v;
        __syncthreads();
    }
    const int num_segs = s_part[255];
    int run = (tid > 0) ? s_part[tid - 1] : 0;
    for (int t = t0; t < t0 + CHUNK; ++t) {
        int bnd = (t == 0) || (s_pred[t] != s_pred[t - 1]);
        if (bnd) { run++; s_start[run - 1] = t; }
    }
    __syncthreads();

    // ---- scan 2: keep -> compacted positions; emit (start,count) ----
    int lk = 0;
    for (int s = t0; s < t0 + CHUNK; ++s) {
        if (s < num_segs && s_pred[s_start[s]] != -1) lk++;
    }
    __syncthreads();             // everyone done reading old s_part prefixes
    s_part[tid] = lk;
    __syncthreads();
    for (int off = 1; off < 256; off <<= 1) {
        int v = (tid >= off) ? s_part[tid - off] : 0;
        __syncthreads();
        s_part[tid] += v;
        __syncthreads();
    }
    int pos = (tid > 0) ? s_part[tid - 1] : 0;
    for (int s = t0; s < t0 + CHUNK; ++s) {
        if (s < num_segs) {
            const int st = s_start[s];
            if (s_pred[st] != -1) {
                const int end = (s + 1 < num_segs) ? s_start[s + 1] : TT;
                g_start[(size_t)b * TT + pos] = st;
                g_count[(size_t)b * TT + pos] = end - st;
                pos++;
            }
        }
    }
    if (tid == 0) g_newsz[b] = s_part[255];
}

// ---------------- K3: segment means -> compacted rows; zero tail; pad ----------------
// One wave (64 lanes = 64 cols) per output row.
__global__ __launch_bounds__(256) void k_out(const float* __restrict__ logits,
                                             const int* __restrict__ g_start,
                                             const int* __restrict__ g_count,
                                             const int* __restrict__ g_newsz,
                                             float* __restrict__ out_logits,
                                             float* __restrict__ out_pad) {
    const int lane = threadIdx.x & 63;
    const int wave = threadIdx.x >> 6;
    const int wavesPerBlock = blockDim.x >> 6;
    const int gw = blockIdx.x * wavesPerBlock + wave;
    const int nw = gridDim.x * wavesPerBlock;

    for (int row = gw; row < BB * TT; row += nw) {
        const int b = row >> 13;          // / TT
        const int p = row & (TT - 1);     // % TT
        const int nsz = g_newsz[b];
        float val = 0.0f;
        if (p < nsz) {
            const int st  = g_start[row];
            const int cnt = g_count[row];
            const float* src = logits + ((size_t)b * TT + st) * CC + lane;
            float acc = 0.0f;
            for (int f = 0; f < cnt; ++f) acc += src[(size_t)f * CC];
            val = acc / (float)cnt;
        }
        out_logits[(size_t)row * CC + lane] = val;
        if (lane == 0) out_pad[row] = (p >= nsz) ? 1.0f : 0.0f;
    }
}

extern "C" void kernel_launch(void* const* d_in, const int* in_sizes, int n_in,
                              void* d_out, int out_size, void* d_ws, size_t ws_size,
                              hipStream_t stream) {
    const float* logits = (const float*)d_in[0];
    const int*   mask   = (const int*)d_in[1];   // jax bool -> int32 (harness rule)

    int* preds   = (int*)d_ws;                   // B*T
    int* g_start = preds   + (size_t)BB * TT;    // B*T
    int* g_count = g_start + (size_t)BB * TT;    // B*T
    int* g_newsz = g_count + (size_t)BB * TT;    // B

    float* out_logits = (float*)d_out;
    float* out_pad    = out_logits + (size_t)BB * TT * CC;

    hipLaunchKernelGGL(k_argmax, dim3(2048), dim3(256), 0, stream,
                       logits, mask, preds);
    hipLaunchKernelGGL(k_rle, dim3(BB), dim3(256), 0, stream,
                       preds, g_start, g_count, g_newsz);
    hipLaunchKernelGGL(k_out, dim3(2048), dim3(256), 0, stream,
                       logits, g_start, g_count, g_newsz, out_logits, out_pad);
}

// Round 2
// 93.641 us; speedup vs baseline: 1.5252x; 1.5252x over previous
//
#include <hip/hip_runtime.h>

#define BB 64
#define TT 8192
#define CC 64

// ---------------- K1: masked argmax over C=64 -> preds[B*T] ----------------
// 16 lanes per frame, float4 loads (16B/lane). Tie-break: first (lowest) index.
__global__ __launch_bounds__(256) void k_argmax(const float* __restrict__ logits,
                                                const int* __restrict__ mask,
                                                int* __restrict__ preds) {
    const int lane = threadIdx.x & 63;
    const int wave = threadIdx.x >> 6;
    const int sub  = lane & 15;   // column group within frame
    const int fidx = lane >> 4;   // frame within group of 4
    const int wavesPerBlock = blockDim.x >> 6;
    const int gw = blockIdx.x * wavesPerBlock + wave;
    const int nw = gridDim.x * wavesPerBlock;
    const int ngroups = (BB * TT) >> 2;   // 4 frames per wave-iteration

    for (int g = gw; g < ngroups; g += nw) {
        const int f = g * 4 + fidx;
        const float4 v = *reinterpret_cast<const float4*>(
            logits + (size_t)f * CC + sub * 4);
        float bv = v.x; int bi = sub * 4;
        if (v.y > bv) { bv = v.y; bi = sub * 4 + 1; }
        if (v.z > bv) { bv = v.z; bi = sub * 4 + 2; }
        if (v.w > bv) { bv = v.w; bi = sub * 4 + 3; }
        // reduce across the 16 lanes of this frame (xor keeps us in-group)
        #pragma unroll
        for (int off = 1; off < 16; off <<= 1) {
            float ov = __shfl_xor(bv, off);
            int   oi = __shfl_xor(bi, off);
            if (ov > bv || (ov == bv && oi < bi)) { bv = ov; bi = oi; }
        }
        if (sub == 0) {
            preds[f] = mask[f] ? -1 : bi;
        }
    }
}

// ---------------- K2: per-batch RLE + compaction scans ----------------
// One block per batch. LDS: preds row (32K) + seg_start (32K) + scan partials.
__global__ __launch_bounds__(256) void k_rle(const int* __restrict__ preds,
                                             int* __restrict__ g_start,
                                             int* __restrict__ g_count,
                                             int* __restrict__ g_newsz) {
    __shared__ int s_pred[TT];
    __shared__ int s_start[TT];
    __shared__ int s_part[256];
    const int b   = blockIdx.x;
    const int tid = threadIdx.x;
    const int CHUNK = TT / 256;     // 32
    const int t0 = tid * CHUNK;

    // load preds row (int4 vectorized)
    {
        const int4* src = reinterpret_cast<const int4*>(preds + (size_t)b * TT);
        int4* dst = reinterpret_cast<int4*>(s_pred);
        for (int i = tid; i < TT / 4; i += 256) dst[i] = src[i];
    }
    __syncthreads();

    // ---- scan 1: boundaries -> segment starts ----
    int local = 0;
    for (int t = t0; t < t0 + CHUNK; ++t) {
        int bnd = (t == 0) || (s_pred[t] != s_pred[t - 1]);
        local += bnd;
    }
    s_part[tid] = local;
    __syncthreads();
    for (int off = 1; off < 256; off <<= 1) {
        int v = (tid >= off) ? s_part[tid - off] : 0;
        __syncthreads();
        s_part[tid] += v;
        __syncthreads();
    }
    const int num_segs = s_part[255];
    int run = (tid > 0) ? s_part[tid - 1] : 0;
    for (int t = t0; t < t0 + CHUNK; ++t) {
        int bnd = (t == 0) || (s_pred[t] != s_pred[t - 1]);
        if (bnd) { run++; s_start[run - 1] = t; }
    }
    __syncthreads();

    // ---- scan 2: keep -> compacted positions; emit (start,count) ----
    int lk = 0;
    for (int s = t0; s < t0 + CHUNK; ++s) {
        if (s < num_segs && s_pred[s_start[s]] != -1) lk++;
    }
    __syncthreads();             // everyone done reading old s_part prefixes
    s_part[tid] = lk;
    __syncthreads();
    for (int off = 1; off < 256; off <<= 1) {
        int v = (tid >= off) ? s_part[tid - off] : 0;
        __syncthreads();
        s_part[tid] += v;
        __syncthreads();
    }
    int pos = (tid > 0) ? s_part[tid - 1] : 0;
    for (int s = t0; s < t0 + CHUNK; ++s) {
        if (s < num_segs) {
            const int st = s_start[s];
            if (s_pred[st] != -1) {
                const int end = (s + 1 < num_segs) ? s_start[s + 1] : TT;
                g_start[(size_t)b * TT + pos] = st;
                g_count[(size_t)b * TT + pos] = end - st;
                pos++;
            }
        }
    }
    if (tid == 0) g_newsz[b] = s_part[255];
}

// ---------------- K3: segment means -> compacted rows; zero tail; pad ----------------
// 16 lanes per output row (float4 = 16B/lane), 4 rows per wave per iteration.
__global__ __launch_bounds__(256) void k_out(const float* __restrict__ logits,
                                             const int* __restrict__ g_start,
                                             const int* __restrict__ g_count,
                                             const int* __restrict__ g_newsz,
                                             float* __restrict__ out_logits,
                                             float* __restrict__ out_pad) {
    __shared__ int s_nsz[BB];
    if (threadIdx.x < BB) s_nsz[threadIdx.x] = g_newsz[threadIdx.x];
    __syncthreads();

    const int lane = threadIdx.x & 63;
    const int wave = threadIdx.x >> 6;
    const int sub  = lane & 15;   // column quad within row
    const int ridx = lane >> 4;   // row within group of 4
    const int wavesPerBlock = blockDim.x >> 6;
    const int gw = blockIdx.x * wavesPerBlock + wave;
    const int nw = gridDim.x * wavesPerBlock;
    const int ngroups = (BB * TT) >> 2;   // 4 rows per wave-iteration

    for (int g = gw; g < ngroups; g += nw) {
        const int row = g * 4 + ridx;
        const int b = row >> 13;          // / TT
        const int p = row & (TT - 1);     // % TT
        const int nsz = s_nsz[b];
        float4 val = make_float4(0.f, 0.f, 0.f, 0.f);
        if (p < nsz) {
            const int st  = g_start[row];
            const int cnt = g_count[row];
            const float* src = logits + ((size_t)b * TT + st) * CC + sub * 4;
            float4 acc = *reinterpret_cast<const float4*>(src);
            for (int f = 1; f < cnt; ++f) {
                const float4 v = *reinterpret_cast<const float4*>(src + (size_t)f * CC);
                acc.x += v.x; acc.y += v.y; acc.z += v.z; acc.w += v.w;
            }
            const float inv = 1.0f / (float)cnt;
            val = make_float4(acc.x * inv, acc.y * inv, acc.z * inv, acc.w * inv);
        }
        *reinterpret_cast<float4*>(out_logits + (size_t)row * CC + sub * 4) = val;
        if (sub == 0) out_pad[row] = (p >= nsz) ? 1.0f : 0.0f;
    }
}

extern "C" void kernel_launch(void* const* d_in, const int* in_sizes, int n_in,
                              void* d_out, int out_size, void* d_ws, size_t ws_size,
                              hipStream_t stream) {
    const float* logits = (const float*)d_in[0];
    const int*   mask   = (const int*)d_in[1];   // jax bool -> int32 (harness rule)

    int* preds   = (int*)d_ws;                   // B*T
    int* g_start = preds   + (size_t)BB * TT;    // B*T
    int* g_count = g_start + (size_t)BB * TT;    // B*T
    int* g_newsz = g_count + (size_t)BB * TT;    // B

    float* out_logits = (float*)d_out;
    float* out_pad    = out_logits + (size_t)BB * TT * CC;

    hipLaunchKernelGGL(k_argmax, dim3(2048), dim3(256), 0, stream,
                       logits, mask, preds);
    hipLaunchKernelGGL(k_rle, dim3(BB), dim3(256), 0, stream,
                       preds, g_start, g_count, g_newsz);
    hipLaunchKernelGGL(k_out, dim3(2048), dim3(256), 0, stream,
                       logits, g_start, g_count, g_newsz, out_logits, out_pad);
}

// Round 3
// 79.321 us; speedup vs baseline: 1.8005x; 1.1805x over previous
//
#include <hip/hip_runtime.h>

#define BB 64
#define TT 8192
#define CC 64

// DPP cross-lane helpers (VALU-only, no LDS). CTRL: 0x141 = row_half_mirror
// (lane^7 within each 8-group), 0x4E = quad_perm [2,3,0,1] (lane^2),
// 0xB1 = quad_perm [1,0,3,2] (lane^1). All stay within an 8-lane group.
template<int CTRL>
__device__ __forceinline__ float dppf(float x) {
    return __int_as_float(__builtin_amdgcn_update_dpp(
        0, __float_as_int(x), CTRL, 0xF, 0xF, true));
}
template<int CTRL>
__device__ __forceinline__ int dppi(int x) {
    return __builtin_amdgcn_update_dpp(0, x, CTRL, 0xF, 0xF, true);
}

// ---------------- K1: masked argmax over C=64 -> preds[B*T] ----------------
// 8 lanes per frame, 8 cols/lane (2x float4), DPP-only reduction.
// Tie-break: first (lowest) index, exact vs np.argmax.
__global__ __launch_bounds__(256) void k_argmax(const float* __restrict__ logits,
                                                const int* __restrict__ mask,
                                                int* __restrict__ preds) {
    const int lane = threadIdx.x & 63;
    const int wave = threadIdx.x >> 6;
    const int sub  = lane & 7;    // column octet within frame
    const int fidx = lane >> 3;   // frame within group of 8
    const int wavesPerBlock = blockDim.x >> 6;
    const int gw = blockIdx.x * wavesPerBlock + wave;
    const int nw = gridDim.x * wavesPerBlock;
    const int ngroups = (BB * TT) >> 3;   // 8 frames per wave-iteration

    #pragma unroll 2
    for (int g = gw; g < ngroups; g += nw) {
        const int f = g * 8 + fidx;
        const float* row = logits + (size_t)f * CC + sub * 8;
        const float4 v0 = *reinterpret_cast<const float4*>(row);
        const float4 v1 = *reinterpret_cast<const float4*>(row + 4);
        // local max over 8 cols
        float m = fmaxf(fmaxf(fmaxf(v0.x, v0.y), fmaxf(v0.z, v0.w)),
                        fmaxf(fmaxf(v1.x, v1.y), fmaxf(v1.z, v1.w)));
        // 8-lane max reduce via DPP rotations/mirrors (pure VALU)
        m = fmaxf(m, dppf<0x141>(m));   // ^7
        m = fmaxf(m, dppf<0x4E>(m));    // ^2
        m = fmaxf(m, dppf<0xB1>(m));    // ^1
        // local first index equal to global max
        const int c0 = sub * 8;
        int li = 64;
        if (v1.w == m) li = c0 + 7;
        if (v1.z == m) li = c0 + 6;
        if (v1.y == m) li = c0 + 5;
        if (v1.x == m) li = c0 + 4;
        if (v0.w == m) li = c0 + 3;
        if (v0.z == m) li = c0 + 2;
        if (v0.y == m) li = c0 + 1;
        if (v0.x == m) li = c0 + 0;
        // 8-lane min-index reduce
        li = min(li, dppi<0x141>(li));
        li = min(li, dppi<0x4E>(li));
        li = min(li, dppi<0xB1>(li));
        if (sub == 0) preds[f] = mask[f] ? -1 : li;
    }
}

// ---------------- K2: per-batch RLE + compaction scans ----------------
// One block (1024 threads) per batch. LDS: preds row + seg_start + partials.
__global__ __launch_bounds__(1024) void k_rle(const int* __restrict__ preds,
                                              int* __restrict__ g_start,
                                              int* __restrict__ g_count,
                                              int* __restrict__ g_newsz) {
    __shared__ int s_pred[TT];
    __shared__ int s_start[TT];
    __shared__ int s_part[1024];
    const int b   = blockIdx.x;
    const int tid = threadIdx.x;
    const int NT  = 1024;
    const int CHUNK = TT / NT;     // 8
    const int t0 = tid * CHUNK;

    // load preds row (int4 vectorized)
    {
        const int4* src = reinterpret_cast<const int4*>(preds + (size_t)b * TT);
        int4* dst = reinterpret_cast<int4*>(s_pred);
        for (int i = tid; i < TT / 4; i += NT) dst[i] = src[i];
    }
    __syncthreads();

    // ---- scan 1: boundaries -> segment starts ----
    int local = 0;
    for (int t = t0; t < t0 + CHUNK; ++t) {
        int bnd = (t == 0) || (s_pred[t] != s_pred[t - 1]);
        local += bnd;
    }
    s_part[tid] = local;
    __syncthreads();
    for (int off = 1; off < NT; off <<= 1) {
        int v = (tid >= off) ? s_part[tid - off] : 0;
        __syncthreads();
        s_part[tid] += v;
        __syncthreads();
    }
    const int num_segs = s_part[NT - 1];
    int run = (tid > 0) ? s_part[tid - 1] : 0;
    for (int t = t0; t < t0 + CHUNK; ++t) {
        int bnd = (t == 0) || (s_pred[t] != s_pred[t - 1]);
        if (bnd) { run++; s_start[run - 1] = t; }
    }
    __syncthreads();

    // ---- scan 2: keep -> compacted positions; emit (start,count) ----
    int lk = 0;
    for (int s = t0; s < t0 + CHUNK; ++s) {
        if (s < num_segs && s_pred[s_start[s]] != -1) lk++;
    }
    __syncthreads();
    s_part[tid] = lk;
    __syncthreads();
    for (int off = 1; off < NT; off <<= 1) {
        int v = (tid >= off) ? s_part[tid - off] : 0;
        __syncthreads();
        s_part[tid] += v;
        __syncthreads();
    }
    int pos = (tid > 0) ? s_part[tid - 1] : 0;
    for (int s = t0; s < t0 + CHUNK; ++s) {
        if (s < num_segs) {
            const int st = s_start[s];
            if (s_pred[st] != -1) {
                const int end = (s + 1 < num_segs) ? s_start[s + 1] : TT;
                g_start[(size_t)b * TT + pos] = st;
                g_count[(size_t)b * TT + pos] = end - st;
                pos++;
            }
        }
    }
    if (tid == 0) g_newsz[b] = s_part[NT - 1];
}

// ---------------- K3: segment means -> compacted rows; zero tail; pad ----------------
// 16 lanes per output row (float4 = 16B/lane), 4 rows per wave per iteration.
__global__ __launch_bounds__(256) void k_out(const float* __restrict__ logits,
                                             const int* __restrict__ g_start,
                                             const int* __restrict__ g_count,
                                             const int* __restrict__ g_newsz,
                                             float* __restrict__ out_logits,
                                             float* __restrict__ out_pad) {
    __shared__ int s_nsz[BB];
    if (threadIdx.x < BB) s_nsz[threadIdx.x] = g_newsz[threadIdx.x];
    __syncthreads();

    const int lane = threadIdx.x & 63;
    const int wave = threadIdx.x >> 6;
    const int sub  = lane & 15;   // column quad within row
    const int ridx = lane >> 4;   // row within group of 4
    const int wavesPerBlock = blockDim.x >> 6;
    const int gw = blockIdx.x * wavesPerBlock + wave;
    const int nw = gridDim.x * wavesPerBlock;
    const int ngroups = (BB * TT) >> 2;   // 4 rows per wave-iteration

    for (int g = gw; g < ngroups; g += nw) {
        const int row = g * 4 + ridx;
        const int b = row >> 13;          // / TT
        const int p = row & (TT - 1);     // % TT
        const int nsz = s_nsz[b];
        float4 val = make_float4(0.f, 0.f, 0.f, 0.f);
        if (p < nsz) {
            const int st  = g_start[row];
            const int cnt = g_count[row];
            const float* src = logits + ((size_t)b * TT + st) * CC + sub * 4;
            float4 acc = *reinterpret_cast<const float4*>(src);
            for (int f = 1; f < cnt; ++f) {
                const float4 v = *reinterpret_cast<const float4*>(src + (size_t)f * CC);
                acc.x += v.x; acc.y += v.y; acc.z += v.z; acc.w += v.w;
            }
            const float inv = 1.0f / (float)cnt;
            val = make_float4(acc.x * inv, acc.y * inv, acc.z * inv, acc.w * inv);
        }
        *reinterpret_cast<float4*>(out_logits + (size_t)row * CC + sub * 4) = val;
        if (sub == 0) out_pad[row] = (p >= nsz) ? 1.0f : 0.0f;
    }
}

extern "C" void kernel_launch(void* const* d_in, const int* in_sizes, int n_in,
                              void* d_out, int out_size, void* d_ws, size_t ws_size,
                              hipStream_t stream) {
    const float* logits = (const float*)d_in[0];
    const int*   mask   = (const int*)d_in[1];   // jax bool -> int32 (harness rule)

    int* preds   = (int*)d_ws;                   // B*T
    int* g_start = preds   + (size_t)BB * TT;    // B*T
    int* g_count = g_start + (size_t)BB * TT;    // B*T
    int* g_newsz = g_count + (size_t)BB * TT;    // B

    float* out_logits = (float*)d_out;
    float* out_pad    = out_logits + (size_t)BB * TT * CC;

    hipLaunchKernelGGL(k_argmax, dim3(2048), dim3(256), 0, stream,
                       logits, mask, preds);
    hipLaunchKernelGGL(k_rle, dim3(BB), dim3(1024), 0, stream,
                       preds, g_start, g_count, g_newsz);
    hipLaunchKernelGGL(k_out, dim3(2048), dim3(256), 0, stream,
                       logits, g_start, g_count, g_newsz, out_logits, out_pad);
}